// Round 6
// baseline (1358.219 us; speedup 1.0000x reference)
//
#include <hip/hip_runtime.h>
#include <math.h>

constexpr int N = 50000;
constexpr int E = 800000;
constexpr int H = 64;
constexpr int NWAVE = 12500;          // N/4 nodes-per-wave mapping (4 nodes per wave)
constexpr int SCB = 49;               // scan blocks per graph: 49*1024 >= N
constexpr int RNG = 8;                // histogram ranges per graph
constexpr int BPR = 8;                // edge slices per graph
constexpr int BINS = N / RNG;         // 6250 bins per range
constexpr int ES   = E / BPR;         // 100000 edges per slice

typedef unsigned short ushort_t;
typedef unsigned int uint_t;

// ---- workspace layout (element offsets) ----
constexpr size_t X_OFF    = 0;                          // N*H
constexpr size_t NO_OFF   = X_OFF + (size_t)N*H;        // N   deg_out^-1/2
constexpr size_t NI_OFF   = NO_OFF + N;                 // N   deg_in^-1/2
constexpr size_t EL_OFF   = NI_OFF + N;                 // N+1 GAT el (incl supernode)
constexpr size_t ER_OFF   = EL_OFF + (N+1);             // N   GAT er
constexpr size_t EE_OFF   = ER_OFF + N;                 // E   per-edge exp(e-m) (CSR order)
constexpr size_t IS_OFF   = EE_OFF + E;                 // N   1/softmax-denominator
constexpr size_t ASLF_OFF = IS_OFF + N;                 // N   self-loop numerator
constexpr size_t ASUP_OFF = ASLF_OFF + N;               // N   supernode numerator
constexpr size_t GF = ((ASUP_OFF + N + 255)/256)*256;

constexpr size_t RP_OFF = 0;                            // N+1 row_ptr (CSR by dst)
constexpr size_t CT_OFF = RP_OFF + (N+1);               // N   in-degree count
constexpr size_t SS_OFF = CT_OFF + N;                   // E   src sorted by dst
constexpr size_t GI = ((SS_OFF + E + 255)/256)*256;

constexpr size_t GH = (size_t)(N+1)*64;                 // bf16 h rows (row N = supernode)

// bf16 helpers (RNE)
__device__ inline uint_t bfpack2(float a, float b){
  uint_t ua=__float_as_uint(a), ub=__float_as_uint(b);
  uint_t ra=(ua + 0x7fffu + ((ua>>16)&1u))>>16;
  uint_t rb=(ub + 0x7fffu + ((ub>>16)&1u))>>16;
  return ra | (rb<<16);
}
__device__ inline float bf2f(ushort_t u){ return __uint_as_float(((uint_t)u)<<16); }
__device__ inline float bflo(uint_t u){ return __uint_as_float(u<<16); }
__device__ inline float bfhi(uint_t u){ return __uint_as_float(u & 0xffff0000u); }

// ---- prep: range-partitioned LDS histograms, zero global atomics ----
__global__ __launch_bounds__(1024) void k_hist(int* parts_ct, int* parts_no,
    const int* s0,const int* d0,const int* s1,const int* d1,const int* s2,const int* d2) {
  int sl = blockIdx.x, r = blockIdx.y, g = blockIdx.z;
  const int* s = g==0?s0:(g==1?s1:s2);
  const int* d = g==0?d0:(g==1?d1:d2);
  __shared__ int hc[BINS];
  __shared__ int hn[BINS];
  for (int i=threadIdx.x;i<BINS;i+=1024){ hc[i]=0; hn[i]=0; }
  __syncthreads();
  int lo = r*BINS, hi = lo+BINS;
  int e0 = sl*ES, e1 = e0+ES;
  for (int e=e0+threadIdx.x; e<e1; e+=1024){
    int ds = d[e], sr = s[e];
    if (ds>=lo && ds<hi) atomicAdd(&hc[ds-lo],1);
    if (sr>=lo && sr<hi) atomicAdd(&hn[sr-lo],1);
  }
  __syncthreads();
  size_t base = ((size_t)g*BPR + sl)*N + lo;
  for (int i=threadIdx.x;i<BINS;i+=1024){
    parts_ct[base+i]=hc[i];
    parts_no[base+i]=hn[i];
  }
}

// ---- hierarchical exclusive scan of cnt -> rp (all parallel) ----
__global__ __launch_bounds__(1024) void k_scan_local(int* ib, int* pt, const int* parts_ct) {
  int g = blockIdx.y;
  int* ig = ib + (size_t)g*GI;
  int i = blockIdx.x*1024 + threadIdx.x;
  int c = 0;
  if (i < N){
    #pragma unroll
    for (int s=0;s<BPR;s++) c += parts_ct[((size_t)g*BPR+s)*N + i];
    ig[CT_OFF + i] = c;
  }
  __shared__ int sh[1024];
  sh[threadIdx.x] = c; __syncthreads();
  #pragma unroll
  for (int off=1; off<1024; off<<=1){
    int t = (threadIdx.x>=off) ? sh[threadIdx.x-off] : 0;
    __syncthreads();
    sh[threadIdx.x] += t;
    __syncthreads();
  }
  if (i < N) ig[RP_OFF + i] = sh[threadIdx.x] - c;       // local exclusive
  if (threadIdx.x == 1023) pt[g*SCB + blockIdx.x] = sh[1023];
}

__global__ void k_scan_part(int* pt) {
  int g = blockIdx.x;
  __shared__ int sh[SCB];
  int t = threadIdx.x;
  if (t < SCB) sh[t] = pt[g*SCB + t];
  __syncthreads();
  if (t == 0){
    int run = 0;
    for (int b=0;b<SCB;b++){ int c = sh[b]; sh[b] = run; run += c; }
  }
  __syncthreads();
  if (t < SCB) pt[g*SCB + t] = sh[t];
}

__global__ __launch_bounds__(1024) void k_scan_apply(float* fb, int* ib, const int* pt,
                                                     const int* parts_no) {
  int g = blockIdx.y;
  float* fg = fb + (size_t)g*GF;
  int* ig = ib + (size_t)g*GI;
  int i = blockIdx.x*1024 + threadIdx.x;
  if (i >= N) return;
  int base = pt[g*SCB + blockIdx.x];
  int r = ig[RP_OFF + i] + base;
  ig[RP_OFF + i] = r;
  int c = ig[CT_OFF + i];
  int o = 0;
  #pragma unroll
  for (int s=0;s<BPR;s++) o += parts_no[((size_t)g*BPR+s)*N + i];
  fg[NI_OFF + i] = rsqrtf((float)(c+1));                 // +1 self loop
  fg[NO_OFF + i] = rsqrtf((float)(o+1));
  if (i == N-1) ig[RP_OFF + N] = r + c;
}

// per-(slice,bin) exclusive prefix over slices -> exact scatter offsets
__global__ __launch_bounds__(256) void k_slice_off(const int* ib, const int* parts_ct, int* off) {
  int g = blockIdx.y;
  int i = blockIdx.x*256 + threadIdx.x;
  if (i >= N) return;
  int base = ib[(size_t)g*GI + RP_OFF + i];
  #pragma unroll
  for (int s=0;s<BPR;s++){
    size_t idx = ((size_t)g*BPR+s)*N + i;
    off[idx] = base;
    base += parts_ct[idx];
  }
}

// scatter: LDS cursors per range, plain scattered store (no global atomics)
__global__ __launch_bounds__(1024) void k_scatter_r(int* ib, const int* off,
    const int* s0,const int* d0,const int* s1,const int* d1,const int* s2,const int* d2) {
  int sl = blockIdx.x, r = blockIdx.y, g = blockIdx.z;
  const int* s = g==0?s0:(g==1?s1:s2);
  const int* d = g==0?d0:(g==1?d1:d2);
  int* ss = ib + (size_t)g*GI + SS_OFF;
  __shared__ int cur[BINS];
  int lo = r*BINS;
  size_t ob = ((size_t)g*BPR + sl)*N + lo;
  for (int i=threadIdx.x;i<BINS;i+=1024) cur[i] = off[ob+i];
  __syncthreads();
  int e0 = sl*ES, e1 = e0+ES;
  for (int e=e0+threadIdx.x; e<e1; e+=1024){
    int ds = d[e];
    if (ds>=lo && ds<lo+BINS){
      int pos = atomicAdd(&cur[ds-lo],1);
      ss[pos] = s[e];
    }
  }
}

__global__ __launch_bounds__(256) void k_copyx(float* fb, const float* x0,const float* x1,const float* x2) {
  int i = blockIdx.x*256 + threadIdx.x;
  int g = blockIdx.y;
  const float* x = g==0?x0:(g==1?x1:x2);
  if (i < N*H/4) {
    ((float4*)(fb + (size_t)g*GF + X_OFF))[i] = ((const float4*)x)[i];
  }
}

// h = bf16( (x @ W) * no[row] )  -> hb (gather operand, halved bytes)
__global__ __launch_bounds__(256) void k_mm_gcn(float* fb, ushort_t* hb,
    const float* W0,const float* W1,const float* W2) {
  int g = blockIdx.y;
  const float* W = g==0?W0:(g==1?W1:W2);
  __shared__ float Ws[64*64];
  for (int i=threadIdx.x; i<4096; i+=256) Ws[i] = W[i];
  __syncthreads();
  int row = blockIdx.x*256 + threadIdx.x;
  if (row >= N) return;
  float* fg = fb + (size_t)g*GF;
  const float4* x4 = (const float4*)(fg + X_OFF + (size_t)row*H);
  float4 xr[16];
  #pragma unroll
  for (int k=0;k<16;k++) xr[k] = x4[k];
  float acc[64];
  #pragma unroll
  for (int j=0;j<64;j++) acc[j] = 0.f;
  const float* xs = (const float*)xr;
  #pragma unroll
  for (int k=0;k<64;k++){
    float xk = xs[k];
    #pragma unroll
    for (int j=0;j<64;j++) acc[j] = fmaf(xk, Ws[k*64+j], acc[j]);
  }
  float sc = fg[NO_OFF + row];
  uint_t pk[32];
  #pragma unroll
  for (int j=0;j<32;j++) pk[j] = bfpack2(acc[2*j]*sc, acc[2*j+1]*sc);
  uint4* h4 = (uint4*)(hb + (size_t)g*GH + (size_t)row*64);
  #pragma unroll
  for (int j=0;j<8;j++) h4[j] = ((const uint4*)pk)[j];
}

// h = bf16(x @ Wgat[g]), el/er from fp32 acc
__global__ __launch_bounds__(256) void k_mm_gat(float* fb, ushort_t* hb,
    const float* Wgat, const float* al, const float* ar) {
  int g = blockIdx.y;
  const float* W = Wgat + (size_t)g*4096;
  __shared__ float Ws[64*64];
  __shared__ float als[64], ars[64];
  for (int i=threadIdx.x; i<4096; i+=256) Ws[i] = W[i];
  if (threadIdx.x < 64){ als[threadIdx.x] = al[g*64+threadIdx.x]; ars[threadIdx.x] = ar[g*64+threadIdx.x]; }
  __syncthreads();
  int row = blockIdx.x*256 + threadIdx.x;
  if (row >= N) return;
  float* fg = fb + (size_t)g*GF;
  const float4* x4 = (const float4*)(fg + X_OFF + (size_t)row*H);
  float4 xr[16];
  #pragma unroll
  for (int k=0;k<16;k++) xr[k] = x4[k];
  float acc[64];
  #pragma unroll
  for (int j=0;j<64;j++) acc[j] = 0.f;
  const float* xs = (const float*)xr;
  #pragma unroll
  for (int k=0;k<64;k++){
    float xk = xs[k];
    #pragma unroll
    for (int j=0;j<64;j++) acc[j] = fmaf(xk, Ws[k*64+j], acc[j]);
  }
  uint_t pk[32];
  #pragma unroll
  for (int j=0;j<32;j++) pk[j] = bfpack2(acc[2*j], acc[2*j+1]);
  uint4* h4 = (uint4*)(hb + (size_t)g*GH + (size_t)row*64);
  #pragma unroll
  for (int j=0;j<8;j++) h4[j] = ((const uint4*)pk)[j];
  float el = 0.f, er = 0.f;
  #pragma unroll
  for (int j=0;j<64;j++){ el = fmaf(acc[j], als[j], el); er = fmaf(acc[j], ars[j], er); }
  fg[EL_OFF + row] = el;
  fg[ER_OFF + row] = er;
}

// GCN aggregate: half-wave dual-edge gathers. Lanes 0-31 take edge k+2j,
// lanes 32-63 take edge k+2j+1; each lane loads one uint (2 bf16 features).
// One 8-load chunk covers 16 edges (~one avg node) in a single latency round.
__global__ __launch_bounds__(256) void k_gcn_agg(float* fb, const ushort_t* hb, const int* ib,
    const float* b, float* sm, int g) {
  float* fg = fb + (size_t)g*GF;
  const uint_t* hu = (const uint_t*)(hb + (size_t)g*GH);
  const int* ig = ib + (size_t)g*GI;
  int wave = threadIdx.x >> 6, lane = threadIdx.x & 63;
  int half = lane >> 5, col = lane & 31;
  int w = blockIdx.x*4 + wave;                 // w < NWAVE, N == 4*NWAVE exactly
  const int* rp = ig + RP_OFF;
  const int* ss = ig + SS_OFF;
  float2 bl = make_float2(0.f,0.f);
  if (half==0) bl = ((const float2*)b)[col];
  int nd[4], r0[4], r1[4];
  #pragma unroll
  for (int i=0;i<4;i++){ nd[i] = w + NWAVE*i; r0[i] = rp[nd[i]]; r1[i] = rp[nd[i]+1]; }
  float2 vs = make_float2(0.f,0.f), vm = make_float2(0.f,0.f);
  __shared__ float ssum[4][64];
  __shared__ float smx[4][64];
  #pragma unroll
  for (int i=0;i<4;i++){
    int node = nd[i];
    float accx = 0.f, accy = 0.f;
    if (half==0){
      uint_t u = hu[(size_t)node*32 + col];    // self loop (pre-scaled)
      accx = bflo(u); accy = bfhi(u);
    }
    int s0 = r0[i], s1 = r1[i];
    int k = s0;
    for (; k + 16 <= s1; k += 16){
      int idx[8];
      #pragma unroll
      for (int j=0;j<8;j++) idx[j] = ss[k + 2*j + half];
      #pragma unroll
      for (int j=0;j<8;j++){
        uint_t u = hu[(size_t)idx[j]*32 + col];
        accx += bflo(u); accy += bfhi(u);
      }
    }
    for (; k + 2 <= s1; k += 2){
      uint_t u = hu[(size_t)ss[k+half]*32 + col];
      accx += bflo(u); accy += bfhi(u);
    }
    if (k < s1 && half==0){
      uint_t u = hu[(size_t)ss[k]*32 + col];
      accx += bflo(u); accy += bfhi(u);
    }
    accx += __shfl_xor(accx, 32);
    accy += __shfl_xor(accy, 32);
    if (half==0){
      float ni = fg[NI_OFF + node];
      float vx = fmaf(accx, ni, bl.x); vx = vx > 0.f ? vx : 0.f;
      float vy = fmaf(accy, ni, bl.y); vy = vy > 0.f ? vy : 0.f;
      ((float2*)(fg + X_OFF + (size_t)node*64))[col] = make_float2(vx, vy);
      vs.x += vx; vs.y += vy;
      vm.x = fmaxf(vm.x, vx); vm.y = fmaxf(vm.y, vy);
    }
  }
  if (half==0){
    ssum[wave][2*col] = vs.x; ssum[wave][2*col+1] = vs.y;
    smx[wave][2*col]  = vm.x; smx[wave][2*col+1]  = vm.y;
  }
  __syncthreads();
  if (threadIdx.x < 64){
    int t = threadIdx.x;
    float s = ssum[0][t]+ssum[1][t]+ssum[2][t]+ssum[3][t];
    float mx = fmaxf(fmaxf(smx[0][t],smx[1][t]), fmaxf(smx[2][t],smx[3][t]));
    atomicAdd(&sm[g*64 + t], s);
    atomicMax((int*)sm + 192 + g*64 + t, __float_as_int(mx));  // v>=0: int order == float order
  }
}

__global__ void k_zero_ro(float* sm) {
  int i = threadIdx.x;
  if (i < 384) sm[i] = 0.f;
}

// readout finalize + cross-graph feature exchange + supernode h row (bf16), el[N]
__global__ void k_exchange(float* fb, ushort_t* hb, float* sm, const float* Wx, const float* bx,
                           const float* Wgat, const float* al, int it) {
  int gt = blockIdx.x;     // target graph
  int t = threadIdx.x;     // 64 threads
  int src, widx;
  if ((it & 1) == 0){ src = (gt==0)?1:(gt==1)?2:0; widx = (gt==0)?1:(gt==1)?0:2; }
  else              { src = (gt==0)?2:(gt==1)?0:1; widx = (gt==0)?5:(gt==1)?3:4; }
  __shared__ float ro[128];
  __shared__ float f[64];
  __shared__ float red[64];
  ro[t]      = sm[src*64 + t] * (1.0f/(float)N);
  ro[64 + t] = __int_as_float(((int*)sm)[192 + src*64 + t]);
  __syncthreads();
  float a = bx[widx*64 + t];
  for (int k=0;k<128;k++) a = fmaf(ro[k], Wx[(size_t)widx*8192 + k*64 + t], a);
  a = a > 0.f ? a : 0.f;
  f[t] = a;
  __syncthreads();
  float* fg = fb + (size_t)gt*GF;
  float hs = 0.f;
  for (int k=0;k<64;k++) hs = fmaf(f[k], Wgat[(size_t)gt*4096 + k*64 + t], hs);
  uint_t u = __float_as_uint(hs);
  hb[(size_t)gt*GH + (size_t)N*64 + t] = (ushort_t)((u + 0x7fffu + ((u>>16)&1u))>>16);
  red[t] = hs * al[gt*64 + t];
  __syncthreads();
  if (t == 0){
    float e = 0.f;
    for (int k=0;k<64;k++) e += red[k];
    fg[EL_OFF + N] = e;                      // el for supernode
  }
}

// per-dst softmax prep: store exp(e-m) per CSR edge, denominators, self/sup numerators
__global__ __launch_bounds__(256) void k_gat_prep(float* fb, const int* ib) {
  int i = blockIdx.x*256 + threadIdx.x;
  int g = blockIdx.y;
  if (i >= N) return;
  float* fg = fb + (size_t)g*GF;
  const int* ig = ib + (size_t)g*GI;
  const int* rp = ig + RP_OFF;
  const int* ss = ig + SS_OFF;
  const float* el = fg + EL_OFF;
  float eri = fg[ER_OFF + i];
  float* ee = fg + EE_OFF;
  float elsup = el[N];
  int s0 = rp[i], s1 = rp[i+1];
  auto lk = [](float x){ return x >= 0.f ? x : 0.2f*x; };
  float eself = lk(el[i] + eri);
  float esup  = lk(elsup + eri);
  float m = fmaxf(eself, esup);
  int k = s0;
  for (; k + 4 <= s1; k += 4){
    int i0=ss[k],i1=ss[k+1],i2=ss[k+2],i3=ss[k+3];
    float e0=lk(el[i0]+eri), e1=lk(el[i1]+eri);
    float e2=lk(el[i2]+eri), e3=lk(el[i3]+eri);
    ee[k]=e0; ee[k+1]=e1; ee[k+2]=e2; ee[k+3]=e3;
    m = fmaxf(m, fmaxf(fmaxf(e0,e1), fmaxf(e2,e3)));
  }
  for (; k < s1; k++){
    float e = lk(el[ss[k]] + eri);
    ee[k] = e;
    m = fmaxf(m, e);
  }
  float s = 0.f;
  k = s0;
  for (; k + 4 <= s1; k += 4){
    float t0 = __expf(ee[k]-m),   t1 = __expf(ee[k+1]-m);
    float t2 = __expf(ee[k+2]-m), t3 = __expf(ee[k+3]-m);
    ee[k]=t0; ee[k+1]=t1; ee[k+2]=t2; ee[k+3]=t3;
    s += (t0+t1)+(t2+t3);
  }
  for (; k < s1; k++){
    float t = __expf(ee[k] - m);
    ee[k] = t;
    s += t;
  }
  float tself = __expf(eself - m), tsup = __expf(esup - m);
  s += tself + tsup;
  fg[IS_OFF + i]   = 1.0f / s;
  fg[ASLF_OFF + i] = tself;
  fg[ASUP_OFF + i] = tsup;
}

// GAT aggregation: same half-wave dual-edge scheme with per-edge weights.
__global__ __launch_bounds__(256) void k_gat_agg(float* fb, const ushort_t* hb, const int* ib,
    const float* bgat, int g) {
  float* fg = fb + (size_t)g*GF;
  const uint_t* hu = (const uint_t*)(hb + (size_t)g*GH);
  const int* ig = ib + (size_t)g*GI;
  int wave = threadIdx.x >> 6, lane = threadIdx.x & 63;
  int half = lane >> 5, col = lane & 31;
  int w = blockIdx.x*4 + wave;
  const int* rp = ig + RP_OFF;
  const int* ss = ig + SS_OFF;
  const float* ee = fg + EE_OFF;
  uint_t supu = hu[(size_t)N*32 + col];
  float2 bg = make_float2(0.f,0.f);
  if (half==0) bg = ((const float2*)(bgat + g*64))[col];
  int nd[4], r0[4], r1[4];
  #pragma unroll
  for (int i=0;i<4;i++){ nd[i] = w + NWAVE*i; r0[i] = rp[nd[i]]; r1[i] = rp[nd[i]+1]; }
  #pragma unroll
  for (int i=0;i<4;i++){
    int node = nd[i];
    float accx = 0.f, accy = 0.f;
    if (half==0){
      float aslf = fg[ASLF_OFF + node], asup = fg[ASUP_OFF + node];
      uint_t u = hu[(size_t)node*32 + col];
      accx = aslf*bflo(u) + asup*bflo(supu);
      accy = aslf*bfhi(u) + asup*bfhi(supu);
    }
    int s0 = r0[i], s1 = r1[i];
    int k = s0;
    for (; k + 16 <= s1; k += 16){
      int idx[8]; float wt[8];
      #pragma unroll
      for (int j=0;j<8;j++){ idx[j] = ss[k + 2*j + half]; wt[j] = ee[k + 2*j + half]; }
      #pragma unroll
      for (int j=0;j<8;j++){
        uint_t u = hu[(size_t)idx[j]*32 + col];
        accx = fmaf(wt[j], bflo(u), accx);
        accy = fmaf(wt[j], bfhi(u), accy);
      }
    }
    for (; k + 2 <= s1; k += 2){
      float wt = ee[k+half];
      uint_t u = hu[(size_t)ss[k+half]*32 + col];
      accx = fmaf(wt, bflo(u), accx);
      accy = fmaf(wt, bfhi(u), accy);
    }
    if (k < s1 && half==0){
      float wt = ee[k];
      uint_t u = hu[(size_t)ss[k]*32 + col];
      accx = fmaf(wt, bflo(u), accx);
      accy = fmaf(wt, bfhi(u), accy);
    }
    accx += __shfl_xor(accx, 32);
    accy += __shfl_xor(accy, 32);
    if (half==0){
      float is = fg[IS_OFF + node];
      ((float2*)(fg + X_OFF + (size_t)node*64))[col] =
          make_float2(fmaf(accx, is, bg.x), fmaf(accy, is, bg.y));
    }
  }
}

__global__ __launch_bounds__(384) void k_mlp(const float* sm, const float* W1, const float* b1,
    const float* W2, const float* b2, const float* W3, const float* b3, float* out) {
  __shared__ float nf[384];
  __shared__ float y1[192];
  __shared__ float y2[96];
  __shared__ float z[2];
  int t = threadIdx.x;
  int g = t / 128, j = t % 128;
  nf[t] = (j < 64) ? sm[g*64 + j] * (1.0f/(float)N)
                   : __int_as_float(((const int*)sm)[192 + g*64 + (j-64)]);
  __syncthreads();
  if (t < 192){
    float a = b1[t];
    for (int k=0;k<384;k++) a = fmaf(nf[k], W1[(size_t)k*192 + t], a);
    y1[t] = a > 0.f ? a : 0.f;
  }
  __syncthreads();
  if (t < 96){
    float a = b2[t];
    for (int k=0;k<192;k++) a = fmaf(y1[k], W2[(size_t)k*96 + t], a);
    y2[t] = a > 0.f ? a : 0.f;
  }
  __syncthreads();
  if (t < 2){
    float a = b3[t];
    for (int k=0;k<96;k++) a = fmaf(y2[k], W3[k*2 + t], a);
    z[t] = a;
  }
  __syncthreads();
  if (t == 0){
    float m = fmaxf(z[0], z[1]);
    float l = m + logf(__expf(z[0]-m) + __expf(z[1]-m));
    out[0] = z[0] - l;
    out[1] = z[1] - l;
  }
}

extern "C" void kernel_launch(void* const* d_in, const int* in_sizes, int n_in,
                              void* d_out, int out_size, void* d_ws, size_t ws_size,
                              hipStream_t stream) {
  const float* x_s  = (const float*)d_in[0];
  const float* x_g  = (const float*)d_in[1];
  const float* x_t  = (const float*)d_in[2];
  const float* Wc_s = (const float*)d_in[3];
  const float* bc_s = (const float*)d_in[4];
  const float* Wc_g = (const float*)d_in[5];
  const float* bc_g = (const float*)d_in[6];
  const float* Wc_t = (const float*)d_in[7];
  const float* bc_t = (const float*)d_in[8];
  const float* Wx   = (const float*)d_in[9];
  const float* bx   = (const float*)d_in[10];
  const float* Wgat = (const float*)d_in[11];
  const float* al   = (const float*)d_in[12];
  const float* ar   = (const float*)d_in[13];
  const float* bgat = (const float*)d_in[14];
  const float* W1   = (const float*)d_in[15];
  const float* b1   = (const float*)d_in[16];
  const float* W2   = (const float*)d_in[17];
  const float* b2   = (const float*)d_in[18];
  const float* W3   = (const float*)d_in[19];
  const float* b3   = (const float*)d_in[20];
  const int* src_s  = (const int*)d_in[21];
  const int* dst_s  = (const int*)d_in[22];
  const int* src_g  = (const int*)d_in[23];
  const int* dst_g  = (const int*)d_in[24];
  const int* src_t  = (const int*)d_in[25];
  const int* dst_t  = (const int*)d_in[26];

  float* fb = (float*)d_ws;
  int*   ib = (int*)(fb + 3*GF);
  ushort_t* hb = (ushort_t*)(ib + 3*GI);
  float* sm = (float*)(hb + 3*GH);
  int*   pt = (int*)(sm + 384);              // 3*SCB scan partials
  int*   parts_ct = pt + 3*SCB + 64;         // 3*BPR*N
  int*   parts_no = parts_ct + (size_t)3*BPR*N;
  int*   off      = parts_no + (size_t)3*BPR*N;
  float* out = (float*)d_out;

  dim3 b256(256);
  const float* bcs[3][3] = {{bc_s, bc_g, bc_t},{bc_s+64, bc_g+64, bc_t+64},{bc_s+128, bc_g+128, bc_t+128}};

  // graph prep: LDS-histogram counting sort (no global atomics)
  k_hist      <<<dim3(BPR, RNG, 3),  dim3(1024), 0, stream>>>(parts_ct, parts_no, src_s,dst_s, src_g,dst_g, src_t,dst_t);
  k_scan_local<<<dim3(SCB, 3),       dim3(1024), 0, stream>>>(ib, pt, parts_ct);
  k_scan_part <<<dim3(3),              dim3(64), 0, stream>>>(pt);
  k_scan_apply<<<dim3(SCB, 3),       dim3(1024), 0, stream>>>(fb, ib, pt, parts_no);
  k_slice_off <<<dim3((N+255)/256, 3),     b256, 0, stream>>>(ib, parts_ct, off);
  k_scatter_r <<<dim3(BPR, RNG, 3),  dim3(1024), 0, stream>>>(ib, off, src_s,dst_s, src_g,dst_g, src_t,dst_t);
  k_copyx     <<<dim3((N*H/4+255)/256, 3), b256, 0, stream>>>(fb, x_s, x_g, x_t);

  for (int it = 0; it < 2; ++it) {
    k_zero_ro <<<1, 384, 0, stream>>>(sm);
    k_mm_gcn  <<<dim3((N+255)/256, 3), b256, 0, stream>>>(fb, hb, Wc_s + it*4096, Wc_g + it*4096, Wc_t + it*4096);
    for (int g = 0; g < 3; ++g)
      k_gcn_agg <<<dim3(NWAVE/4), b256, 0, stream>>>(fb, hb, ib, bcs[it][g], sm, g);
    k_exchange<<<dim3(3), dim3(64), 0, stream>>>(fb, hb, sm, Wx, bx, Wgat, al, it);
    k_mm_gat  <<<dim3((N+255)/256, 3), b256, 0, stream>>>(fb, hb, Wgat, al, ar);
    k_gat_prep<<<dim3((N+255)/256, 3), b256, 0, stream>>>(fb, ib);
    for (int g = 0; g < 3; ++g)
      k_gat_agg <<<dim3(NWAVE/4), b256, 0, stream>>>(fb, hb, ib, bgat, g);
  }

  // final layer readouts + MLP head
  k_zero_ro <<<1, 384, 0, stream>>>(sm);
  k_mm_gcn  <<<dim3((N+255)/256, 3), b256, 0, stream>>>(fb, hb, Wc_s + 2*4096, Wc_g + 2*4096, Wc_t + 2*4096);
  for (int g = 0; g < 3; ++g)
    k_gcn_agg <<<dim3(NWAVE/4), b256, 0, stream>>>(fb, hb, ib, bcs[2][g], sm, g);
  k_mlp     <<<1, 384, 0, stream>>>(sm, W1, b1, W2, b2, W3, b3, out);
}